// Round 1
// baseline (2957.902 us; speedup 1.0000x reference)
//
#include <hip/hip_runtime.h>
#include <hip/hip_bf16.h>

#define BB   16384
#define TT   60
#define HH   64

__device__ __forceinline__ float bcast(float v, int k) {
    return __uint_as_float(__builtin_amdgcn_readlane(__float_as_uint(v), k));
}
__device__ __forceinline__ float sigm(float x) { return 1.0f / (1.0f + __expf(-x)); }

// ---------------- Kernel A: surface MLP init + LSTM1 (reverse time) ----------------
// one wave per batch element; lane = hidden unit. Writes rnn1out_f[b][t][h] (bf16) to ws.
__global__ __launch_bounds__(1024) void k_lstm1(
    const float* __restrict__ xmain, const float* __restrict__ aux,
    const float* __restrict__ Ws1, const float* __restrict__ bs1,
    const float* __restrict__ Ws2, const float* __restrict__ bs2,
    const float* __restrict__ Wih1, const float* __restrict__ Whh1,
    const float* __restrict__ bih1, const float* __restrict__ bhh1,
    __hip_bfloat16* __restrict__ rnn1f)
{
    __shared__ __hip_bfloat16 w1[64 * 256];   // [k][lane][gate] packed, 32KB
    __shared__ float wih[256 * 4];            // [row][x], 4KB
    __shared__ float bb[256];
    __shared__ float s_ws1[64 * 4], s_ws2[64 * 4];
    __shared__ float s_bs1[64], s_bs2[64];

    const int tid = threadIdx.x;
    for (int e = tid; e < 64 * 256; e += 1024) {
        int row = e >> 6, k = e & 63;          // Whh1[row][k]
        int g = row >> 6, l = row & 63;
        w1[(k << 8) + (l << 2) + g] = __float2bfloat16(Whh1[e]);
    }
    wih[tid] = Wih1[tid];                      // exactly 1024 elements
    if (tid < 256) bb[tid] = bih1[tid] + bhh1[tid];
    if (tid < 192) {
        s_ws1[(tid / 3) * 4 + (tid % 3)] = Ws1[tid];
        s_ws2[(tid / 3) * 4 + (tid % 3)] = Ws2[tid];
    }
    if (tid < 64) { s_bs1[tid] = bs1[tid]; s_bs2[tid] = bs2[tid]; }
    __syncthreads();

    const int lane = tid & 63;
    const int b = blockIdx.x * 16 + (tid >> 6);

    const float a0 = aux[b * 3 + 0], a1 = aux[b * 3 + 1], a2 = aux[b * 3 + 2];
    float h = s_ws1[lane * 4 + 0] * a0 + s_ws1[lane * 4 + 1] * a1 + s_ws1[lane * 4 + 2] * a2 + s_bs1[lane];
    float c = tanhf(s_ws2[lane * 4 + 0] * a0 + s_ws2[lane * 4 + 1] * a1 + s_ws2[lane * 4 + 2] * a2 + s_bs2[lane]);

    float wi[4][4];
    #pragma unroll
    for (int g = 0; g < 4; ++g)
        #pragma unroll
        for (int x = 0; x < 4; ++x)
            wi[g][x] = wih[((g << 6) + lane) * 4 + x];
    const float bbl0 = bb[lane], bbl1 = bb[64 + lane], bbl2 = bb[128 + lane], bbl3 = bb[192 + lane];

    const float* xb = xmain + (size_t)b * (TT * 4);
    __hip_bfloat16* ob = rnn1f + (size_t)b * (TT * HH);
    const uint2* wp1 = (const uint2*)w1;

    for (int s = 0; s < TT; ++s) {
        const int t = TT - 1 - s;              // reverse time
        const float4 xv = *(const float4*)(xb + t * 4);
        float g0 = bbl0 + wi[0][0] * xv.x + wi[0][1] * xv.y + wi[0][2] * xv.z + wi[0][3] * xv.w;
        float g1 = bbl1 + wi[1][0] * xv.x + wi[1][1] * xv.y + wi[1][2] * xv.z + wi[1][3] * xv.w;
        float g2 = bbl2 + wi[2][0] * xv.x + wi[2][1] * xv.y + wi[2][2] * xv.z + wi[2][3] * xv.w;
        float g3 = bbl3 + wi[3][0] * xv.x + wi[3][1] * xv.y + wi[3][2] * xv.z + wi[3][3] * xv.w;
        #pragma unroll 8
        for (int k = 0; k < 64; ++k) {
            const float hk = bcast(h, k);
            const uint2 wp = wp1[(k << 6) + lane];
            g0 = fmaf(__uint_as_float(wp.x << 16), hk, g0);
            g1 = fmaf(__uint_as_float(wp.x & 0xffff0000u), hk, g1);
            g2 = fmaf(__uint_as_float(wp.y << 16), hk, g2);
            g3 = fmaf(__uint_as_float(wp.y & 0xffff0000u), hk, g3);
        }
        const float gi = sigm(g0), gf = sigm(g1), gg = tanhf(g2), go = sigm(g3);
        c = fmaf(gf, c, gi * gg);
        h = go * tanhf(c);
        ob[t * 64 + lane] = __float2bfloat16(h);
    }
}

// ---------------- Kernel B: LSTM2 (forward time) + fused heads ----------------
__global__ __launch_bounds__(1024) void k_lstm2(
    const __hip_bfloat16* __restrict__ rnn1f,
    const float* __restrict__ hx2, const float* __restrict__ cx2,
    const float* __restrict__ Wih2, const float* __restrict__ Whh2,
    const float* __restrict__ bih2, const float* __restrict__ bhh2,
    const float* __restrict__ Wlat, const float* __restrict__ blat,
    const float* __restrict__ Wout, const float* __restrict__ bout,
    const float* __restrict__ Wsfc, const float* __restrict__ bsfc,
    float* __restrict__ out)
{
    __shared__ __hip_bfloat16 w2i[64 * 256];  // [k][lane][gate], 32KB
    __shared__ __hip_bfloat16 w2h[64 * 256];  // 32KB
    __shared__ float bb[256];
    __shared__ float wc[256];                 // folded Wout@Wlat, [o][k]
    __shared__ float bc[4];
    __shared__ float wsf[192];
    __shared__ float bsf[3];

    const int tid = threadIdx.x;
    for (int e = tid; e < 64 * 256; e += 1024) {
        int row = e >> 6, k = e & 63, g = row >> 6, l = row & 63;
        int di = (k << 8) + (l << 2) + g;
        w2i[di] = __float2bfloat16(Wih2[e]);
        w2h[di] = __float2bfloat16(Whh2[e]);
    }
    if (tid < 256) {
        bb[tid] = bih2[tid] + bhh2[tid];
        int o = tid >> 6, k = tid & 63;
        float s = 0.f;
        for (int j = 0; j < 64; ++j) s += Wout[o * 64 + j] * Wlat[j * 64 + k];
        wc[tid] = s;
    }
    if (tid < 4) {
        float s = 0.f;
        for (int j = 0; j < 64; ++j) s += Wout[tid * 64 + j] * blat[j];
        bc[tid] = s + bout[tid];
    }
    if (tid < 192) wsf[tid] = Wsfc[tid];
    if (tid < 3) bsf[tid] = bsfc[tid];
    __syncthreads();

    const int lane = tid & 63;
    const int b = blockIdx.x * 16 + (tid >> 6);

    float h = hx2[b * 64 + lane];
    float c = cx2[b * 64 + lane];
    const float bbl0 = bb[lane], bbl1 = bb[64 + lane], bbl2 = bb[128 + lane], bbl3 = bb[192 + lane];
    const __hip_bfloat16* ib = rnn1f + (size_t)b * (TT * HH);
    float* outb = out + (size_t)b * (TT * 4);
    const uint2* wpi = (const uint2*)w2i;
    const uint2* wph = (const uint2*)w2h;

    for (int t = 0; t < TT; ++t) {
        const float h1 = __bfloat162float(ib[t * 64 + lane]);
        float g0 = bbl0, g1 = bbl1, g2 = bbl2, g3 = bbl3;
        #pragma unroll 4
        for (int k = 0; k < 64; ++k) {
            const float h1k = bcast(h1, k);
            const float h2k = bcast(h, k);
            const uint2 wi = wpi[(k << 6) + lane];
            const uint2 wh = wph[(k << 6) + lane];
            g0 = fmaf(__uint_as_float(wi.x << 16), h1k, g0);
            g0 = fmaf(__uint_as_float(wh.x << 16), h2k, g0);
            g1 = fmaf(__uint_as_float(wi.x & 0xffff0000u), h1k, g1);
            g1 = fmaf(__uint_as_float(wh.x & 0xffff0000u), h2k, g1);
            g2 = fmaf(__uint_as_float(wi.y << 16), h1k, g2);
            g2 = fmaf(__uint_as_float(wh.y << 16), h2k, g2);
            g3 = fmaf(__uint_as_float(wi.y & 0xffff0000u), h1k, g3);
            g3 = fmaf(__uint_as_float(wh.y & 0xffff0000u), h2k, g3);
        }
        const float gi = sigm(g0), gf = sigm(g1), gg = tanhf(g2), go = sigm(g3);
        c = fmaf(gf, c, gi * gg);
        h = go * tanhf(c);

        // fused (Wlat,Wout) head: out[b,t,o] = sum_k wc[o][k]*h[k] + bc[o]
        float p0 = wc[lane] * h, p1 = wc[64 + lane] * h, p2 = wc[128 + lane] * h, p3 = wc[192 + lane] * h;
        #pragma unroll
        for (int m = 1; m < 64; m <<= 1) {
            p0 += __shfl_xor(p0, m, 64);
            p1 += __shfl_xor(p1, m, 64);
            p2 += __shfl_xor(p2, m, 64);
            p3 += __shfl_xor(p3, m, 64);
        }
        if (lane == 0) {
            float4 r = { p0 + bc[0], p1 + bc[1], p2 + bc[2], p3 + bc[3] };
            *(float4*)(outb + t * 4) = r;
        }
    }

    // surface head on last h
    float q0 = wsf[lane] * h, q1 = wsf[64 + lane] * h, q2 = wsf[128 + lane] * h;
    #pragma unroll
    for (int m = 1; m < 64; m <<= 1) {
        q0 += __shfl_xor(q0, m, 64);
        q1 += __shfl_xor(q1, m, 64);
        q2 += __shfl_xor(q2, m, 64);
    }
    if (lane == 0) {
        float* os = out + (size_t)BB * TT * 4 + (size_t)b * 3;
        os[0] = fmaxf(q0 + bsf[0], 0.f);
        os[1] = fmaxf(q1 + bsf[1], 0.f);
        os[2] = fmaxf(q2 + bsf[2], 0.f);
    }
}

extern "C" void kernel_launch(void* const* d_in, const int* in_sizes, int n_in,
                              void* d_out, int out_size, void* d_ws, size_t ws_size,
                              hipStream_t stream) {
    const float* xmain = (const float*)d_in[0];
    const float* aux   = (const float*)d_in[1];
    const float* hx2   = (const float*)d_in[2];
    const float* cx2   = (const float*)d_in[3];
    const float* Ws1   = (const float*)d_in[4];
    const float* bs1   = (const float*)d_in[5];
    const float* Ws2   = (const float*)d_in[6];
    const float* bs2   = (const float*)d_in[7];
    const float* Wih1  = (const float*)d_in[8];
    const float* Whh1  = (const float*)d_in[9];
    const float* bih1  = (const float*)d_in[10];
    const float* bhh1  = (const float*)d_in[11];
    const float* Wih2  = (const float*)d_in[12];
    const float* Whh2  = (const float*)d_in[13];
    const float* bih2  = (const float*)d_in[14];
    const float* bhh2  = (const float*)d_in[15];
    const float* Wlat  = (const float*)d_in[16];
    const float* blat  = (const float*)d_in[17];
    const float* Wout  = (const float*)d_in[18];
    const float* bout  = (const float*)d_in[19];
    const float* Wsfc  = (const float*)d_in[20];
    const float* bsfc  = (const float*)d_in[21];

    __hip_bfloat16* rnn1f = (__hip_bfloat16*)d_ws;   // [B][T][H] bf16 = 126MB
    float* out = (float*)d_out;

    dim3 grid(BB / 16), block(1024);
    k_lstm1<<<grid, block, 0, stream>>>(xmain, aux, Ws1, bs1, Ws2, bs2,
                                        Wih1, Whh1, bih1, bhh1, rnn1f);
    k_lstm2<<<grid, block, 0, stream>>>(rnn1f, hx2, cx2, Wih2, Whh2, bih2, bhh2,
                                        Wlat, blat, Wout, bout, Wsfc, bsfc, out);
}

// Round 2
// 449.837 us; speedup vs baseline: 6.5755x; 6.5755x over previous
//
#include <hip/hip_runtime.h>
#include <hip/hip_bf16.h>

#define BB 16384
#define TT 60

typedef short bf16x8 __attribute__((ext_vector_type(8)));
typedef float f32x4 __attribute__((ext_vector_type(4)));

__device__ __forceinline__ unsigned short f2bs(float f) {
    __hip_bfloat16 h = __float2bfloat16(f);
    return __builtin_bit_cast(unsigned short, h);
}
__device__ __forceinline__ float sigm(float x) { return 1.f / (1.f + __expf(-x)); }
__device__ __forceinline__ float ftanh(float x) { float e = __expf(2.f * x); return 1.f - 2.f / (e + 1.f); }

// ---------------- Kernel A: surface MLP init + LSTM1 (reverse time), MFMA ----------------
// wave = 16 batch elems. kext layout: 0..63 = h (Whh1), 64..67 = x (Wih1), 68..127 = 0.
__global__ __launch_bounds__(256, 1) void k_lstm1(
    const float* __restrict__ xmain, const float* __restrict__ aux,
    const float* __restrict__ Ws1, const float* __restrict__ bs1,
    const float* __restrict__ Ws2, const float* __restrict__ bs2,
    const float* __restrict__ Wih1, const float* __restrict__ Whh1,
    const float* __restrict__ bih1, const float* __restrict__ bhh1,
    unsigned short* __restrict__ rnn1t)
{
    __shared__ unsigned short wB[256 * 128];     // [gaterow][kext] bf16, XOR-swizzled, 64KB
    __shared__ unsigned short hBall[4 * 16 * 128]; // per-wave bounce [m][kext], 16KB
    __shared__ float bb[256];
    __shared__ float baux[192];
    __shared__ float sw1[192], sw2[192], sb1[64], sb2[64];

    const int tid = threadIdx.x;
    unsigned int* wB32 = (unsigned int*)wB;
    unsigned int* hB32 = (unsigned int*)hBall;
    #pragma unroll 4
    for (int e = tid; e < 16384; e += 256) wB32[e] = 0;
    #pragma unroll 4
    for (int e = tid; e < 4096; e += 256) hB32[e] = 0;
    __syncthreads();

    #pragma unroll 4
    for (int e = tid; e < 16384; e += 256) {
        int row = e >> 6, k = e & 63;
        wB[(row * 128 + k) ^ ((row & 7) << 3)] = f2bs(Whh1[e]);
    }
    #pragma unroll 2
    for (int e = tid; e < 1024; e += 256) {
        int row = e >> 2, k = 64 + (e & 3);
        wB[(row * 128 + k) ^ ((row & 7) << 3)] = f2bs(Wih1[e]);
    }
    bb[tid] = bih1[tid] + bhh1[tid];
    if (tid < 192) {
        baux[tid] = aux[blockIdx.x * 192 + tid];
        sw1[tid] = Ws1[tid];
        sw2[tid] = Ws2[tid];
    }
    if (tid < 64) { sb1[tid] = bs1[tid]; sb2[tid] = bs2[tid]; }
    __syncthreads();

    const int wave = tid >> 6, lane = tid & 63;
    const int row16 = lane & 15, quad = lane >> 4;
    const int b0 = blockIdx.x * 64 + wave * 16;
    unsigned short* hB = hBall + wave * 2048;
    const int swz = (row16 & 7) << 3;

    float fb[16];
    #pragma unroll
    for (int n = 0; n < 16; ++n) fb[n] = bb[n * 16 + row16];

    // h0/c0 in C layout: m = quad*4+r, j = hj*16+row16
    f32x4 cc[4];
    #pragma unroll
    for (int hj = 0; hj < 4; ++hj) {
        #pragma unroll
        for (int r = 0; r < 4; ++r) {
            int m = quad * 4 + r;
            int j = hj * 16 + row16;
            float a0v = baux[(wave * 16 + m) * 3 + 0];
            float a1v = baux[(wave * 16 + m) * 3 + 1];
            float a2v = baux[(wave * 16 + m) * 3 + 2];
            float h0 = sw1[j * 3] * a0v + sw1[j * 3 + 1] * a1v + sw1[j * 3 + 2] * a2v + sb1[j];
            float c0 = ftanh(sw2[j * 3] * a0v + sw2[j * 3 + 1] * a1v + sw2[j * 3 + 2] * a2v + sb2[j]);
            cc[hj][r] = c0;
            hB[(m * 128 + j) ^ ((m & 7) << 3)] = f2bs(h0);
        }
    }

    #pragma unroll 1
    for (int s = 0; s < TT; ++s) {
        const int t = TT - 1 - s;
        // stage x_t into bounce kext 64..67 (lanes 0..15 handle m = lane)
        if (lane < 16) {
            float4 xv = ((const float4*)xmain)[(size_t)(b0 + lane) * TT + t];
            uint2 p;
            p.x = (unsigned int)f2bs(xv.x) | ((unsigned int)f2bs(xv.y) << 16);
            p.y = (unsigned int)f2bs(xv.z) | ((unsigned int)f2bs(xv.w) << 16);
            *(uint2*)&hB[(lane * 128 + 64) ^ ((lane & 7) << 3)] = p;
        }
        // A fragments (row = lane&15, k = quad*8 + j within chunk)
        bf16x8 a0 = *(const bf16x8*)&hB[(row16 * 128 + 0 + quad * 8) ^ swz];
        bf16x8 a1 = *(const bf16x8*)&hB[(row16 * 128 + 32 + quad * 8) ^ swz];
        bf16x8 a2 = *(const bf16x8*)&hB[(row16 * 128 + 64 + quad * 8) ^ swz];

        // deferred global store of previous h (slot t+1), straight from A frags
        if (s > 0) {
            size_t g = ((size_t)(t + 1) * BB + b0 + row16) * 64 + quad * 8;
            *(bf16x8*)&rnn1t[g] = a0;
            *(bf16x8*)&rnn1t[g + 32] = a1;
        }

        f32x4 acc[16];
        #pragma unroll
        for (int n = 0; n < 16; ++n) { f32x4 v = {fb[n], fb[n], fb[n], fb[n]}; acc[n] = v; }
        #pragma unroll
        for (int n = 0; n < 16; ++n) {
            const int br = (n * 16 + row16) * 128;
            bf16x8 b0f = *(const bf16x8*)&wB[(br + 0 + quad * 8) ^ swz];
            bf16x8 b1f = *(const bf16x8*)&wB[(br + 32 + quad * 8) ^ swz];
            bf16x8 b2f = *(const bf16x8*)&wB[(br + 64 + quad * 8) ^ swz];
            acc[n] = __builtin_amdgcn_mfma_f32_16x16x32_bf16(a0, b0f, acc[n], 0, 0, 0);
            acc[n] = __builtin_amdgcn_mfma_f32_16x16x32_bf16(a1, b1f, acc[n], 0, 0, 0);
            acc[n] = __builtin_amdgcn_mfma_f32_16x16x32_bf16(a2, b2f, acc[n], 0, 0, 0);
        }
        // elementwise; gate tile n = g*4 + hj
        #pragma unroll
        for (int hj = 0; hj < 4; ++hj) {
            #pragma unroll
            for (int r = 0; r < 4; ++r) {
                float gi = sigm(acc[hj][r]);
                float gf = sigm(acc[4 + hj][r]);
                float gg = ftanh(acc[8 + hj][r]);
                float go = sigm(acc[12 + hj][r]);
                float cn = gf * cc[hj][r] + gi * gg;
                cc[hj][r] = cn;
                int m = quad * 4 + r;
                hB[(m * 128 + hj * 16 + row16) ^ ((m & 7) << 3)] = f2bs(go * ftanh(cn));
            }
        }
    }
    // final h (t=0)
    {
        bf16x8 a0 = *(const bf16x8*)&hB[(row16 * 128 + 0 + quad * 8) ^ swz];
        bf16x8 a1 = *(const bf16x8*)&hB[(row16 * 128 + 32 + quad * 8) ^ swz];
        size_t g = ((size_t)(b0 + row16)) * 64 + quad * 8;
        *(bf16x8*)&rnn1t[g] = a0;
        *(bf16x8*)&rnn1t[g + 32] = a1;
    }
}

// ---------------- Kernel B: LSTM2 (forward) + fused heads, MFMA ----------------
// kext: 0..63 = h2 (Whh2), 64..127 = h1_t (Wih2).
__global__ __launch_bounds__(256, 1) void k_lstm2(
    const unsigned short* __restrict__ rnn1t,
    const float* __restrict__ hx2, const float* __restrict__ cx2,
    const float* __restrict__ Wih2, const float* __restrict__ Whh2,
    const float* __restrict__ bih2, const float* __restrict__ bhh2,
    const float* __restrict__ Wlat, const float* __restrict__ blat,
    const float* __restrict__ Wout, const float* __restrict__ bout,
    const float* __restrict__ Wsfc, const float* __restrict__ bsfc,
    float* __restrict__ out)
{
    __shared__ unsigned short wB[256 * 128];
    __shared__ unsigned short hBall[4 * 16 * 128];
    __shared__ unsigned short wcB[16 * 64], wsB[16 * 64];
    __shared__ float bb[256], bc4[4], bsf3[3];

    const int tid = threadIdx.x;
    for (int e = tid; e < 512; e += 256) {
        ((unsigned int*)wcB)[e] = 0;
        ((unsigned int*)wsB)[e] = 0;
    }
    __syncthreads();

    #pragma unroll 4
    for (int e = tid; e < 16384; e += 256) {
        int row = e >> 6, k = e & 63;
        int sz = (row & 7) << 3;
        wB[(row * 128 + k) ^ sz] = f2bs(Whh2[e]);
        wB[(row * 128 + 64 + k) ^ sz] = f2bs(Wih2[e]);
    }
    {
        bb[tid] = bih2[tid] + bhh2[tid];
        int o = tid >> 6, k = tid & 63;   // folded head: wc = Wout @ Wlat
        float s = 0.f;
        for (int j = 0; j < 64; ++j) s += Wout[o * 64 + j] * Wlat[j * 64 + k];
        wcB[(o * 64 + k) ^ ((o & 7) << 3)] = f2bs(s);
    }
    if (tid < 4) {
        float s = 0.f;
        for (int j = 0; j < 64; ++j) s += Wout[tid * 64 + j] * blat[j];
        bc4[tid] = s + bout[tid];
    }
    if (tid < 192) {
        int o = tid >> 6, k = tid & 63;
        wsB[(o * 64 + k) ^ ((o & 7) << 3)] = f2bs(Wsfc[tid]);
    }
    if (tid < 3) bsf3[tid] = bsfc[tid];
    __syncthreads();

    const int wave = tid >> 6, lane = tid & 63;
    const int row16 = lane & 15, quad = lane >> 4;
    const int b0 = blockIdx.x * 64 + wave * 16;
    unsigned short* hB = hBall + wave * 2048;
    const int swz = (row16 & 7) << 3;

    float fb[16];
    #pragma unroll
    for (int n = 0; n < 16; ++n) fb[n] = bb[n * 16 + row16];

    bf16x8 wcf0 = *(const bf16x8*)&wcB[(row16 * 64 + 0 + quad * 8) ^ swz];
    bf16x8 wcf1 = *(const bf16x8*)&wcB[(row16 * 64 + 32 + quad * 8) ^ swz];
    const float bcr = (row16 < 4) ? bc4[row16] : 0.f;

    f32x4 cc[4];
    #pragma unroll
    for (int hj = 0; hj < 4; ++hj) {
        #pragma unroll
        for (int r = 0; r < 4; ++r) {
            int m = quad * 4 + r;
            int j = hj * 16 + row16;
            cc[hj][r] = cx2[(size_t)(b0 + m) * 64 + j];
            hB[(m * 128 + j) ^ ((m & 7) << 3)] = f2bs(hx2[(size_t)(b0 + m) * 64 + j]);
        }
    }

    #pragma unroll 1
    for (int t = 0; t < TT; ++t) {
        // stage h1_t into bounce kext 64..127
        {
            size_t g = ((size_t)t * BB + b0 + row16) * 64 + quad * 8;
            bf16x8 v0 = *(const bf16x8*)&rnn1t[g];
            bf16x8 v1 = *(const bf16x8*)&rnn1t[g + 32];
            *(bf16x8*)&hB[(row16 * 128 + 64 + quad * 8) ^ swz] = v0;
            *(bf16x8*)&hB[(row16 * 128 + 96 + quad * 8) ^ swz] = v1;
        }
        bf16x8 a0 = *(const bf16x8*)&hB[(row16 * 128 + 0 + quad * 8) ^ swz];
        bf16x8 a1 = *(const bf16x8*)&hB[(row16 * 128 + 32 + quad * 8) ^ swz];
        bf16x8 a2 = *(const bf16x8*)&hB[(row16 * 128 + 64 + quad * 8) ^ swz];
        bf16x8 a3 = *(const bf16x8*)&hB[(row16 * 128 + 96 + quad * 8) ^ swz];

        // head from h2_{t-1} (a0,a1) -> out slot t-1
        f32x4 hacc = {bcr, bcr, bcr, bcr};
        hacc = __builtin_amdgcn_mfma_f32_16x16x32_bf16(a0, wcf0, hacc, 0, 0, 0);
        hacc = __builtin_amdgcn_mfma_f32_16x16x32_bf16(a1, wcf1, hacc, 0, 0, 0);
        if (t > 0) {
            if (row16 < 4) {
                #pragma unroll
                for (int r = 0; r < 4; ++r)
                    out[((size_t)(b0 + quad * 4 + r) * TT + (t - 1)) * 4 + row16] = hacc[r];
            }
        }

        f32x4 acc[16];
        #pragma unroll
        for (int n = 0; n < 16; ++n) { f32x4 v = {fb[n], fb[n], fb[n], fb[n]}; acc[n] = v; }
        #pragma unroll
        for (int n = 0; n < 16; ++n) {
            const int br = (n * 16 + row16) * 128;
            bf16x8 b0f = *(const bf16x8*)&wB[(br + 0 + quad * 8) ^ swz];
            bf16x8 b1f = *(const bf16x8*)&wB[(br + 32 + quad * 8) ^ swz];
            bf16x8 b2f = *(const bf16x8*)&wB[(br + 64 + quad * 8) ^ swz];
            bf16x8 b3f = *(const bf16x8*)&wB[(br + 96 + quad * 8) ^ swz];
            acc[n] = __builtin_amdgcn_mfma_f32_16x16x32_bf16(a0, b0f, acc[n], 0, 0, 0);
            acc[n] = __builtin_amdgcn_mfma_f32_16x16x32_bf16(a1, b1f, acc[n], 0, 0, 0);
            acc[n] = __builtin_amdgcn_mfma_f32_16x16x32_bf16(a2, b2f, acc[n], 0, 0, 0);
            acc[n] = __builtin_amdgcn_mfma_f32_16x16x32_bf16(a3, b3f, acc[n], 0, 0, 0);
        }
        #pragma unroll
        for (int hj = 0; hj < 4; ++hj) {
            #pragma unroll
            for (int r = 0; r < 4; ++r) {
                float gi = sigm(acc[hj][r]);
                float gf = sigm(acc[4 + hj][r]);
                float gg = ftanh(acc[8 + hj][r]);
                float go = sigm(acc[12 + hj][r]);
                float cn = gf * cc[hj][r] + gi * gg;
                cc[hj][r] = cn;
                int m = quad * 4 + r;
                hB[(m * 128 + hj * 16 + row16) ^ ((m & 7) << 3)] = f2bs(go * ftanh(cn));
            }
        }
    }
    // final head (t=59) + surface head
    {
        bf16x8 a0 = *(const bf16x8*)&hB[(row16 * 128 + 0 + quad * 8) ^ swz];
        bf16x8 a1 = *(const bf16x8*)&hB[(row16 * 128 + 32 + quad * 8) ^ swz];
        f32x4 hacc = {bcr, bcr, bcr, bcr};
        hacc = __builtin_amdgcn_mfma_f32_16x16x32_bf16(a0, wcf0, hacc, 0, 0, 0);
        hacc = __builtin_amdgcn_mfma_f32_16x16x32_bf16(a1, wcf1, hacc, 0, 0, 0);
        if (row16 < 4) {
            #pragma unroll
            for (int r = 0; r < 4; ++r)
                out[((size_t)(b0 + quad * 4 + r) * TT + 59) * 4 + row16] = hacc[r];
        }
        bf16x8 wsf0 = *(const bf16x8*)&wsB[(row16 * 64 + 0 + quad * 8) ^ swz];
        bf16x8 wsf1 = *(const bf16x8*)&wsB[(row16 * 64 + 32 + quad * 8) ^ swz];
        const float bsr = (row16 < 3) ? bsf3[row16] : 0.f;
        f32x4 sacc = {bsr, bsr, bsr, bsr};
        sacc = __builtin_amdgcn_mfma_f32_16x16x32_bf16(a0, wsf0, sacc, 0, 0, 0);
        sacc = __builtin_amdgcn_mfma_f32_16x16x32_bf16(a1, wsf1, sacc, 0, 0, 0);
        if (row16 < 3) {
            float* osfc = out + (size_t)BB * TT * 4;
            #pragma unroll
            for (int r = 0; r < 4; ++r)
                osfc[(size_t)(b0 + quad * 4 + r) * 3 + row16] = fmaxf(sacc[r], 0.f);
        }
    }
}

extern "C" void kernel_launch(void* const* d_in, const int* in_sizes, int n_in,
                              void* d_out, int out_size, void* d_ws, size_t ws_size,
                              hipStream_t stream) {
    const float* xmain = (const float*)d_in[0];
    const float* aux   = (const float*)d_in[1];
    const float* hx2   = (const float*)d_in[2];
    const float* cx2   = (const float*)d_in[3];
    const float* Ws1   = (const float*)d_in[4];
    const float* bs1   = (const float*)d_in[5];
    const float* Ws2   = (const float*)d_in[6];
    const float* bs2   = (const float*)d_in[7];
    const float* Wih1  = (const float*)d_in[8];
    const float* Whh1  = (const float*)d_in[9];
    const float* bih1  = (const float*)d_in[10];
    const float* bhh1  = (const float*)d_in[11];
    const float* Wih2  = (const float*)d_in[12];
    const float* Whh2  = (const float*)d_in[13];
    const float* bih2  = (const float*)d_in[14];
    const float* bhh2  = (const float*)d_in[15];
    const float* Wlat  = (const float*)d_in[16];
    const float* blat  = (const float*)d_in[17];
    const float* Wout  = (const float*)d_in[18];
    const float* bout  = (const float*)d_in[19];
    const float* Wsfc  = (const float*)d_in[20];
    const float* bsfc  = (const float*)d_in[21];

    unsigned short* rnn1t = (unsigned short*)d_ws;   // [T][B][64] bf16
    float* out = (float*)d_out;

    dim3 grid(256), block(256);
    k_lstm1<<<grid, block, 0, stream>>>(xmain, aux, Ws1, bs1, Ws2, bs2,
                                        Wih1, Whh1, bih1, bhh1, rnn1t);
    k_lstm2<<<grid, block, 0, stream>>>(rnn1t, hx2, cx2, Wih2, Whh2, bih2, bhh2,
                                        Wlat, blat, Wout, bout, Wsfc, bsfc, out);
}

// Round 3
// 431.843 us; speedup vs baseline: 6.8495x; 1.0417x over previous
//
#include <hip/hip_runtime.h>
#include <hip/hip_bf16.h>

#define BB 16384
#define TT 60

typedef short bf16x8 __attribute__((ext_vector_type(8)));
typedef float f32x4 __attribute__((ext_vector_type(4)));

__device__ __forceinline__ unsigned short f2bs(float f) {
    __hip_bfloat16 h = __float2bfloat16(f);
    return __builtin_bit_cast(unsigned short, h);
}
__device__ __forceinline__ float sigm(float x) { return 1.f / (1.f + __expf(-x)); }
__device__ __forceinline__ float ftanh(float x) { float e = __expf(2.f * x); return 1.f - 2.f / (e + 1.f); }

// ---------------- Kernel A: surface MLP init + LSTM1 (reverse time), MFMA ----------------
// Block = 1024 thr = 16 waves = 4 batch-tiles x 4 gate-split waves.
// kext: 0..63 = h (Whh1), 64..67 = x (Wih1), 68..95 = 0. Wave hj owns gate tiles {hj,hj+4,hj+8,hj+12}.
__global__ __launch_bounds__(1024) void k_lstm1(
    const float* __restrict__ xmain, const float* __restrict__ aux,
    const float* __restrict__ Ws1, const float* __restrict__ bs1,
    const float* __restrict__ Ws2, const float* __restrict__ bs2,
    const float* __restrict__ Wih1, const float* __restrict__ Whh1,
    const float* __restrict__ bih1, const float* __restrict__ bhh1,
    unsigned short* __restrict__ rnn1t)
{
    __shared__ unsigned short wB[256 * 128];        // 64KB, XOR-swizzled
    __shared__ unsigned short hBall[4 * 2 * 2048];  // 4 bt x 2 buf x (16x128), 32KB
    __shared__ float bb[256];
    __shared__ float baux[192], sw1[192], sw2[192], sb1[64], sb2[64];

    const int tid = threadIdx.x;
    unsigned int* wB32 = (unsigned int*)wB;
    unsigned int* hB32 = (unsigned int*)hBall;
    #pragma unroll
    for (int e = tid; e < 16384; e += 1024) wB32[e] = 0;
    #pragma unroll
    for (int e = tid; e < 8192; e += 1024) hB32[e] = 0;
    __syncthreads();

    #pragma unroll
    for (int e = tid; e < 16384; e += 1024) {
        int row = e >> 6, k = e & 63;
        wB[(row * 128 + k) ^ ((row & 7) << 3)] = f2bs(Whh1[e]);
    }
    {   // Wih1: 1024 elements, one per thread
        int row = tid >> 2, k = 64 + (tid & 3);
        wB[(row * 128 + k) ^ ((row & 7) << 3)] = f2bs(Wih1[tid]);
    }
    if (tid < 256) bb[tid] = bih1[tid] + bhh1[tid];
    if (tid < 192) {
        baux[tid] = aux[blockIdx.x * 192 + tid];
        sw1[tid] = Ws1[tid];
        sw2[tid] = Ws2[tid];
    }
    if (tid < 64) { sb1[tid] = bs1[tid]; sb2[tid] = bs2[tid]; }
    __syncthreads();

    const int wv = tid >> 6, lane = tid & 63;
    const int bt = wv >> 2, hj = wv & 3;
    const int row16 = lane & 15, quad = lane >> 4;
    const int b0 = blockIdx.x * 64 + bt * 16;
    const int swz = (row16 & 7) << 3;
    unsigned short* hb0 = hBall + bt * 4096;

    // hoist B fragments (step-invariant weights): tiles n = hj + 4i
    bf16x8 wf[4][3];
    #pragma unroll
    for (int i = 0; i < 4; ++i) {
        const int br = ((hj + 4 * i) * 16 + row16) * 128;
        #pragma unroll
        for (int f = 0; f < 3; ++f)
            wf[i][f] = *(const bf16x8*)&wB[(br + f * 32 + quad * 8) ^ swz];
    }
    float fb[4];
    #pragma unroll
    for (int i = 0; i < 4; ++i) fb[i] = bb[(hj + 4 * i) * 16 + row16];

    // init h0/c0 at (m=quad*4+r, j=hj*16+row16)
    const int j = hj * 16 + row16;
    f32x4 cc;
    {
        const float w10 = sw1[j * 3], w11 = sw1[j * 3 + 1], w12 = sw1[j * 3 + 2];
        const float w20 = sw2[j * 3], w21 = sw2[j * 3 + 1], w22 = sw2[j * 3 + 2];
        #pragma unroll
        for (int r = 0; r < 4; ++r) {
            const int m = quad * 4 + r;
            float a0v = baux[(bt * 16 + m) * 3], a1v = baux[(bt * 16 + m) * 3 + 1], a2v = baux[(bt * 16 + m) * 3 + 2];
            float h0 = w10 * a0v + w11 * a1v + w12 * a2v + sb1[j];
            cc[r] = ftanh(w20 * a0v + w21 * a1v + w22 * a2v + sb2[j]);
            hb0[(m * 128 + j) ^ ((m & 7) << 3)] = f2bs(h0);
        }
    }
    if (hj == 2 && lane < 16) {   // stage x_59 into buf0
        float4 xv = ((const float4*)xmain)[(size_t)(b0 + lane) * TT + 59];
        uint2 p2;
        p2.x = (unsigned)f2bs(xv.x) | ((unsigned)f2bs(xv.y) << 16);
        p2.y = (unsigned)f2bs(xv.z) | ((unsigned)f2bs(xv.w) << 16);
        *(uint2*)&hb0[(lane * 128 + 64) ^ ((lane & 7) << 3)] = p2;
    }
    __syncthreads();

    int p = 0;
    #pragma unroll 1
    for (int s = 0; s < TT; ++s) {
        const int t = TT - 1 - s;
        unsigned short* hB = hb0 + p * 2048;
        unsigned short* hBn = hb0 + (p ^ 1) * 2048;
        float4 xv;
        if (hj == 2 && lane < 16 && t > 0)   // prefetch x_{t-1}
            xv = ((const float4*)xmain)[(size_t)(b0 + lane) * TT + (t - 1)];
        bf16x8 a0 = *(const bf16x8*)&hB[(row16 * 128 + 0 + quad * 8) ^ swz];
        bf16x8 a1 = *(const bf16x8*)&hB[(row16 * 128 + 32 + quad * 8) ^ swz];
        bf16x8 a2 = *(const bf16x8*)&hB[(row16 * 128 + 64 + quad * 8) ^ swz];
        if (s > 0) {   // global store h_{t+1} straight from A frags
            if (hj == 0) *(bf16x8*)&rnn1t[((size_t)(t + 1) * BB + b0 + row16) * 64 + quad * 8] = a0;
            if (hj == 1) *(bf16x8*)&rnn1t[((size_t)(t + 1) * BB + b0 + row16) * 64 + 32 + quad * 8] = a1;
        }
        f32x4 ac[4];
        #pragma unroll
        for (int i = 0; i < 4; ++i) { f32x4 v = {fb[i], fb[i], fb[i], fb[i]}; ac[i] = v; }
        #pragma unroll
        for (int i = 0; i < 4; ++i) {
            ac[i] = __builtin_amdgcn_mfma_f32_16x16x32_bf16(a0, wf[i][0], ac[i], 0, 0, 0);
            ac[i] = __builtin_amdgcn_mfma_f32_16x16x32_bf16(a1, wf[i][1], ac[i], 0, 0, 0);
            ac[i] = __builtin_amdgcn_mfma_f32_16x16x32_bf16(a2, wf[i][2], ac[i], 0, 0, 0);
        }
        #pragma unroll
        for (int r = 0; r < 4; ++r) {
            float gi = sigm(ac[0][r]);
            float gf = sigm(ac[1][r]);
            float gg = ftanh(ac[2][r]);
            float go = sigm(ac[3][r]);
            float cn = gf * cc[r] + gi * gg;
            cc[r] = cn;
            const int m = quad * 4 + r;
            hBn[(m * 128 + j) ^ ((m & 7) << 3)] = f2bs(go * ftanh(cn));
        }
        if (hj == 2 && lane < 16 && t > 0) {
            uint2 p2;
            p2.x = (unsigned)f2bs(xv.x) | ((unsigned)f2bs(xv.y) << 16);
            p2.y = (unsigned)f2bs(xv.z) | ((unsigned)f2bs(xv.w) << 16);
            *(uint2*)&hBn[(lane * 128 + 64) ^ ((lane & 7) << 3)] = p2;
        }
        __syncthreads();
        p ^= 1;
    }
    // epilogue: store h_0 (slot 0)
    unsigned short* hB = hb0 + p * 2048;
    if (hj == 0) {
        bf16x8 a0 = *(const bf16x8*)&hB[(row16 * 128 + 0 + quad * 8) ^ swz];
        *(bf16x8*)&rnn1t[((size_t)(b0 + row16)) * 64 + quad * 8] = a0;
    }
    if (hj == 1) {
        bf16x8 a1 = *(const bf16x8*)&hB[(row16 * 128 + 32 + quad * 8) ^ swz];
        *(bf16x8*)&rnn1t[((size_t)(b0 + row16)) * 64 + 32 + quad * 8] = a1;
    }
}

// ---------------- Kernel B: LSTM2 (forward) + fused heads, MFMA ----------------
// kext: 0..63 = h2 (Whh2), 64..127 = h1_t (Wih2). Same 4-way gate-split.
__global__ __launch_bounds__(1024) void k_lstm2(
    const unsigned short* __restrict__ rnn1t,
    const float* __restrict__ hx2, const float* __restrict__ cx2,
    const float* __restrict__ Wih2, const float* __restrict__ Whh2,
    const float* __restrict__ bih2, const float* __restrict__ bhh2,
    const float* __restrict__ Wlat, const float* __restrict__ blat,
    const float* __restrict__ Wout, const float* __restrict__ bout,
    const float* __restrict__ Wsfc, const float* __restrict__ bsfc,
    float* __restrict__ out)
{
    __shared__ unsigned short wB[256 * 128];        // 64KB
    __shared__ unsigned short hBall[4 * 2 * 2048];  // 32KB
    __shared__ unsigned short wcB[16 * 64], wsB[16 * 64];
    __shared__ float bb[256], bc4[4], bsf3[3];

    const int tid = threadIdx.x;
    if (tid < 512) {
        ((unsigned int*)wcB)[tid] = 0;
        ((unsigned int*)wsB)[tid] = 0;
    }
    __syncthreads();

    #pragma unroll
    for (int e = tid; e < 16384; e += 1024) {
        int row = e >> 6, k = e & 63;
        int sz = (row & 7) << 3;
        wB[(row * 128 + k) ^ sz] = f2bs(Whh2[e]);
        wB[(row * 128 + 64 + k) ^ sz] = f2bs(Wih2[e]);
    }
    if (tid < 256) {
        bb[tid] = bih2[tid] + bhh2[tid];
        int o = tid >> 6, k = tid & 63;   // folded head: wc = Wout @ Wlat
        float s = 0.f;
        for (int jj = 0; jj < 64; ++jj) s += Wout[o * 64 + jj] * Wlat[jj * 64 + k];
        wcB[(o * 64 + k) ^ ((o & 7) << 3)] = f2bs(s);
    }
    if (tid < 4) {
        float s = 0.f;
        for (int jj = 0; jj < 64; ++jj) s += Wout[tid * 64 + jj] * blat[jj];
        bc4[tid] = s + bout[tid];
    }
    if (tid < 192) {
        int o = tid >> 6, k = tid & 63;
        wsB[(o * 64 + k) ^ ((o & 7) << 3)] = f2bs(Wsfc[tid]);
    }
    if (tid < 3) bsf3[tid] = bsfc[tid];
    __syncthreads();

    const int wv = tid >> 6, lane = tid & 63;
    const int bt = wv >> 2, hj = wv & 3;
    const int row16 = lane & 15, quad = lane >> 4;
    const int b0 = blockIdx.x * 64 + bt * 16;
    const int swz = (row16 & 7) << 3;
    unsigned short* hb0 = hBall + bt * 4096;

    // hoist B frags 0..2 per tile; frag 3 read in-loop (VGPR budget)
    bf16x8 wf[4][3];
    #pragma unroll
    for (int i = 0; i < 4; ++i) {
        const int br = ((hj + 4 * i) * 16 + row16) * 128;
        #pragma unroll
        for (int f = 0; f < 3; ++f)
            wf[i][f] = *(const bf16x8*)&wB[(br + f * 32 + quad * 8) ^ swz];
    }
    float fb[4];
    #pragma unroll
    for (int i = 0; i < 4; ++i) fb[i] = bb[(hj + 4 * i) * 16 + row16];

    bf16x8 wcf0, wcf1, wsf0, wsf1;
    float bcr = 0.f, bsr = 0.f;
    if (hj == 3) {
        wcf0 = *(const bf16x8*)&wcB[(row16 * 64 + 0 + quad * 8) ^ swz];
        wcf1 = *(const bf16x8*)&wcB[(row16 * 64 + 32 + quad * 8) ^ swz];
        bcr = (row16 < 4) ? bc4[row16] : 0.f;
    }
    if (hj == 2) {
        wsf0 = *(const bf16x8*)&wsB[(row16 * 64 + 0 + quad * 8) ^ swz];
        wsf1 = *(const bf16x8*)&wsB[(row16 * 64 + 32 + quad * 8) ^ swz];
        bsr = (row16 < 3) ? bsf3[row16] : 0.f;
    }

    // init h2/c2 at (m=quad*4+r, j=hj*16+row16)
    const int j = hj * 16 + row16;
    f32x4 cc;
    #pragma unroll
    for (int r = 0; r < 4; ++r) {
        const int m = quad * 4 + r;
        cc[r] = cx2[(size_t)(b0 + m) * 64 + j];
        hb0[(m * 128 + j) ^ ((m & 7) << 3)] = f2bs(hx2[(size_t)(b0 + m) * 64 + j]);
    }
    // stage h1_0 into buf0 cols 64..127
    if (hj == 0) {
        bf16x8 v = *(const bf16x8*)&rnn1t[((size_t)(b0 + row16)) * 64 + quad * 8];
        *(bf16x8*)&hb0[(row16 * 128 + 64 + quad * 8) ^ swz] = v;
    }
    if (hj == 1) {
        bf16x8 v = *(const bf16x8*)&rnn1t[((size_t)(b0 + row16)) * 64 + 32 + quad * 8];
        *(bf16x8*)&hb0[(row16 * 128 + 96 + quad * 8) ^ swz] = v;
    }
    __syncthreads();

    int p = 0;
    #pragma unroll 1
    for (int t = 0; t < TT; ++t) {
        unsigned short* hB = hb0 + p * 2048;
        unsigned short* hBn = hb0 + (p ^ 1) * 2048;
        bf16x8 pv;
        if (t < TT - 1) {   // prefetch h1_{t+1}
            if (hj == 0) pv = *(const bf16x8*)&rnn1t[((size_t)(t + 1) * BB + b0 + row16) * 64 + quad * 8];
            if (hj == 1) pv = *(const bf16x8*)&rnn1t[((size_t)(t + 1) * BB + b0 + row16) * 64 + 32 + quad * 8];
        }
        bf16x8 a0 = *(const bf16x8*)&hB[(row16 * 128 + 0 + quad * 8) ^ swz];
        bf16x8 a1 = *(const bf16x8*)&hB[(row16 * 128 + 32 + quad * 8) ^ swz];
        bf16x8 a2 = *(const bf16x8*)&hB[(row16 * 128 + 64 + quad * 8) ^ swz];
        bf16x8 a3 = *(const bf16x8*)&hB[(row16 * 128 + 96 + quad * 8) ^ swz];

        if (hj == 3 && t > 0) {   // head from h2_t (pre-update) -> out slot t-1
            f32x4 hacc = {bcr, bcr, bcr, bcr};
            hacc = __builtin_amdgcn_mfma_f32_16x16x32_bf16(a0, wcf0, hacc, 0, 0, 0);
            hacc = __builtin_amdgcn_mfma_f32_16x16x32_bf16(a1, wcf1, hacc, 0, 0, 0);
            if (row16 < 4) {
                #pragma unroll
                for (int r = 0; r < 4; ++r)
                    out[((size_t)(b0 + quad * 4 + r) * TT + (t - 1)) * 4 + row16] = hacc[r];
            }
        }

        f32x4 ac[4];
        #pragma unroll
        for (int i = 0; i < 4; ++i) { f32x4 v = {fb[i], fb[i], fb[i], fb[i]}; ac[i] = v; }
        #pragma unroll
        for (int i = 0; i < 4; ++i) {
            bf16x8 b3 = *(const bf16x8*)&wB[(((hj + 4 * i) * 16 + row16) * 128 + 96 + quad * 8) ^ swz];
            ac[i] = __builtin_amdgcn_mfma_f32_16x16x32_bf16(a0, wf[i][0], ac[i], 0, 0, 0);
            ac[i] = __builtin_amdgcn_mfma_f32_16x16x32_bf16(a1, wf[i][1], ac[i], 0, 0, 0);
            ac[i] = __builtin_amdgcn_mfma_f32_16x16x32_bf16(a2, wf[i][2], ac[i], 0, 0, 0);
            ac[i] = __builtin_amdgcn_mfma_f32_16x16x32_bf16(a3, b3, ac[i], 0, 0, 0);
        }
        #pragma unroll
        for (int r = 0; r < 4; ++r) {
            float gi = sigm(ac[0][r]);
            float gf = sigm(ac[1][r]);
            float gg = ftanh(ac[2][r]);
            float go = sigm(ac[3][r]);
            float cn = gf * cc[r] + gi * gg;
            cc[r] = cn;
            const int m = quad * 4 + r;
            hBn[(m * 128 + j) ^ ((m & 7) << 3)] = f2bs(go * ftanh(cn));
        }
        if (t < TT - 1) {
            if (hj == 0) *(bf16x8*)&hBn[(row16 * 128 + 64 + quad * 8) ^ swz] = pv;
            if (hj == 1) *(bf16x8*)&hBn[(row16 * 128 + 96 + quad * 8) ^ swz] = pv;
        }
        __syncthreads();
        p ^= 1;
    }
    // epilogue: final head (slot 59) + surface head
    unsigned short* hB = hb0 + p * 2048;
    if (hj == 3) {
        bf16x8 a0 = *(const bf16x8*)&hB[(row16 * 128 + 0 + quad * 8) ^ swz];
        bf16x8 a1 = *(const bf16x8*)&hB[(row16 * 128 + 32 + quad * 8) ^ swz];
        f32x4 hacc = {bcr, bcr, bcr, bcr};
        hacc = __builtin_amdgcn_mfma_f32_16x16x32_bf16(a0, wcf0, hacc, 0, 0, 0);
        hacc = __builtin_amdgcn_mfma_f32_16x16x32_bf16(a1, wcf1, hacc, 0, 0, 0);
        if (row16 < 4) {
            #pragma unroll
            for (int r = 0; r < 4; ++r)
                out[((size_t)(b0 + quad * 4 + r) * TT + 59) * 4 + row16] = hacc[r];
        }
    }
    if (hj == 2) {
        bf16x8 a0 = *(const bf16x8*)&hB[(row16 * 128 + 0 + quad * 8) ^ swz];
        bf16x8 a1 = *(const bf16x8*)&hB[(row16 * 128 + 32 + quad * 8) ^ swz];
        f32x4 sacc = {bsr, bsr, bsr, bsr};
        sacc = __builtin_amdgcn_mfma_f32_16x16x32_bf16(a0, wsf0, sacc, 0, 0, 0);
        sacc = __builtin_amdgcn_mfma_f32_16x16x32_bf16(a1, wsf1, sacc, 0, 0, 0);
        if (row16 < 3) {
            float* osfc = out + (size_t)BB * TT * 4;
            #pragma unroll
            for (int r = 0; r < 4; ++r)
                osfc[(size_t)(b0 + quad * 4 + r) * 3 + row16] = fmaxf(sacc[r], 0.f);
        }
    }
}

extern "C" void kernel_launch(void* const* d_in, const int* in_sizes, int n_in,
                              void* d_out, int out_size, void* d_ws, size_t ws_size,
                              hipStream_t stream) {
    const float* xmain = (const float*)d_in[0];
    const float* aux   = (const float*)d_in[1];
    const float* hx2   = (const float*)d_in[2];
    const float* cx2   = (const float*)d_in[3];
    const float* Ws1   = (const float*)d_in[4];
    const float* bs1   = (const float*)d_in[5];
    const float* Ws2   = (const float*)d_in[6];
    const float* bs2   = (const float*)d_in[7];
    const float* Wih1  = (const float*)d_in[8];
    const float* Whh1  = (const float*)d_in[9];
    const float* bih1  = (const float*)d_in[10];
    const float* bhh1  = (const float*)d_in[11];
    const float* Wih2  = (const float*)d_in[12];
    const float* Whh2  = (const float*)d_in[13];
    const float* bih2  = (const float*)d_in[14];
    const float* bhh2  = (const float*)d_in[15];
    const float* Wlat  = (const float*)d_in[16];
    const float* blat  = (const float*)d_in[17];
    const float* Wout  = (const float*)d_in[18];
    const float* bout  = (const float*)d_in[19];
    const float* Wsfc  = (const float*)d_in[20];
    const float* bsfc  = (const float*)d_in[21];

    unsigned short* rnn1t = (unsigned short*)d_ws;   // [T][B][64] bf16
    float* out = (float*)d_out;

    dim3 grid(256), block(1024);
    k_lstm1<<<grid, block, 0, stream>>>(xmain, aux, Ws1, bs1, Ws2, bs2,
                                        Wih1, Whh1, bih1, bhh1, rnn1t);
    k_lstm2<<<grid, block, 0, stream>>>(rnn1t, hx2, cx2, Wih2, Whh2, bih2, bhh2,
                                        Wlat, blat, Wout, bout, Wsfc, bsfc, out);
}